// Round 10
// baseline (108.208 us; speedup 1.0000x reference)
//
#include <hip/hip_runtime.h>
#include <utility>

#define NQ 18
#define BATCH 64

// ws float-offsets for the fast path
#define VT_OFFC (1u << 24)                      // 64*2^18 state floats first
#define CS_OFFC (VT_OFFC + BATCH * NQ * 4)      // then vt table, then cos/sin table

__device__ __forceinline__ float2 cmulf(float2 a, float2 b) {
    return make_float2(a.x * b.x - a.y * b.y, a.x * b.y + a.y * b.x);
}

template<class F, int... Is>
__device__ __forceinline__ void unroll_impl(F f, std::integer_sequence<int, Is...>) {
    (f(std::integral_constant<int, Is>{}), ...);
}
template<int N, class F>
__device__ __forceinline__ void unroll(F f) {
    unroll_impl(f, std::make_integer_sequence<int, N>{});
}

// ---------------------------------------------------------------------------
// Gate algebra (storage order fixed = logical order at layer 1):
//  ladder = linear map T: s -> s ^ (s>>1)  (final[s] = pre[T s])
//  layer-k RY(qubit q), p = 17-q, conjugated to stored coords:
//    mask m = T^(k-1) e_p ; orientation O = row p of T^-(k-1)
//  Output perm: out[s] = A[T^4 s], T^4 s = s ^ (s>>4).
//
// Inter-pass ws layout: float offset = (x10..15) | (x7..9)<<6 | (x0..3)<<9
//                     | (x4..6)<<13 | (x16..17)<<16 | b<<18
// LDS tile swizzle slot(y) = y ^ ((y>>6)&31) is GF(2)-LINEAR -> per-phase
// addresses hoist to  slot(P_t) ^ slot(K_j)  (runtime base ^ compile-time K).
// ---------------------------------------------------------------------------
struct Gate { int k, p; };
constexpr Gate GT[54] = {
    // pass A phase 0, window x 12..17
    {2,13},{2,14},{2,15},{2,16},{2,17}, {3,14},{3,15},{3,16},{3,17}, {4,15},{4,16},{4,17},
    // phase 1, window x 10..15
    {2,11},{2,12}, {3,12},{3,13}, {4,13},{4,14},
    // phase 2, window x 7..12
    {2,8},{2,9},{2,10}, {3,9},{3,10},{3,11}, {4,10},{4,11},{4,12},
    // phase 3, window x 4..9
    {2,5},{2,6},{2,7}, {3,6},{3,7},{3,8}, {4,7},{4,8},{4,9},
    // pass B, window x 0..6
    {2,0},{2,1},{2,2},{2,3},{2,4},
    {3,0},{3,1},{3,2},{3,3},{3,4},{3,5},
    {4,0},{4,1},{4,2},{4,3},{4,4},{4,5},{4,6},
};
constexpr unsigned gmask(Gate g) {
    return g.k == 2 ? (g.p >= 1 ? 3u << (g.p - 1) : 1u)
         : g.k == 3 ? (g.p >= 2 ? 5u << (g.p - 2) : 1u << g.p)
         : (g.p >= 3 ? 15u << (g.p - 3) : (1u << (g.p + 1)) - 1u);
}
constexpr unsigned gorient(Gate g) {
    return g.k == 2 ? (0x3FFFFu & ~((1u << g.p) - 1u))
         : g.k == 3 ? ((0x15555u << g.p) & 0x3FFFFu)
         : ((0x33333u << g.p) & 0x3FFFFu);
}
constexpr int gcsi(Gate g) { return (g.k - 2) * NQ + (17 - g.p); }

// Apply NG gates (GT[OFF..OFF+NG)) on NR=2^w register window starting at x-bit WL.
template<int WL, int OFF, int NG, int NR>
__device__ __forceinline__ void apply_gates(float* a, unsigned xfix, const float* csn) {
    unroll<NG>([&](auto I) {
        constexpr Gate g = GT[OFF + I.value];
        constexpr unsigned m  = gmask(g);
        constexpr unsigned O  = gorient(g);
        constexpr unsigned mr = (m >> WL) & (unsigned)(NR - 1);
        constexpr unsigned hb = 1u << (g.p - WL);
        constexpr unsigned Or = (O >> WL) & (unsigned)(NR - 1);
        constexpr unsigned Of = O & ~(((unsigned)(NR - 1)) << WL);
        float c = csn[2 * gcsi(g)], s = csn[2 * gcsi(g) + 1];
        float ps = (__popc(xfix & Of) & 1) ? -s : s;
        float ms = -ps;
        unroll<NR>([&](auto R) {
            constexpr int r = R.value;
            if constexpr ((r & (int)hb) == 0) {
                constexpr int r2 = r ^ (int)mr;
                constexpr bool fl = (__builtin_popcount((unsigned)r & Or) & 1) != 0;
                float se = fl ? ms : ps;
                float x0 = a[r], x1 = a[r2];
                a[r]  = c * x0 - se * x1;
                a[r2] = se * x0 + c * x1;
            }
        });
    });
}

// component unpermute by XOR k (k in 0..3): t_c <- r_{c^k}
__device__ __forceinline__ float4 perm4(float4 r, int k) {
    float t0 = r.x, t1 = r.y, t2 = r.z, t3 = r.w;
    if (k & 1) { float x; x=t0;t0=t1;t1=x; x=t2;t2=t3;t3=x; }
    if (k & 2) { float x; x=t0;t0=t2;t2=x; x=t1;t1=t3;t3=x; }
    return make_float4(t0, t1, t2, t3);
}

// prep: vt[b][q] = RY(p0q/2)*RX(x/2)|0> (4 floats), plus cos/sin for layers 1..3
__global__ void k_prep(const float* __restrict__ inputs, const float* __restrict__ params,
                       float* __restrict__ ws) {
    int t = blockIdx.x * blockDim.x + threadIdx.x;
    if (t < BATCH * NQ) {
        int q = t % NQ;
        float x = 0.5f * inputs[t];
        float cx = cosf(x), sx = sinf(x);
        float th = 0.5f * params[q];
        float c = cosf(th), s = sinf(th);
        float* v = ws + VT_OFFC + t * 4;
        v[0] = c * cx;  v[1] = s * sx;     // v0 = c*cx + i*s*sx
        v[2] = s * cx;  v[3] = -c * sx;    // v1 = s*cx - i*c*sx
    } else if (t < BATCH * NQ + 54) {
        int i = t - BATCH * NQ;            // (k-2)*18 + q  -> params[(k-1)*18+q]
        float th = 0.5f * params[NQ + i];
        ws[CS_OFFC + 2 * i]     = cosf(th);
        ws[CS_OFFC + 2 * i + 1] = sinf(th);
    }
}

// pass A: init product (layer 0 folded) + 36 gates on x bits 4..17.
// WG = (b, c4 = x bits 0..3); tile = 2^14 f32 in LDS (4 gate phases).
// All LDS addresses hoisted: slot(P|K) = slot(P) ^ slot(K) (GF2-linear).
__global__ __launch_bounds__(256) void k_passA(const float* __restrict__ ws_tab,
                                               float* __restrict__ ws) {
    __shared__ __align__(16) float lds[16384];   // exactly 64 KiB
    const int b  = blockIdx.x >> 4;
    const int c4 = blockIdx.x & 15;
    const int t  = threadIdx.x;
    const float* vt  = ws_tab + VT_OFFC + b * NQ * 4;
    const float* csn = ws_tab + CS_OFFC;

    // init: complex product, reg bit bp <-> x bit 12+bp <-> qubit 5-bp
    unsigned xf0 = (unsigned)c4 | ((unsigned)t << 4);   // x bits 0..11
    float2 pf = make_float2(1.f, 0.f);
    #pragma unroll
    for (int i = 0; i < 12; ++i) {
        int bit = (xf0 >> i) & 1;
        const float* vq = vt + (17 - i) * 4 + bit * 2;
        pf = cmulf(pf, make_float2(vq[0], vq[1]));
    }
    float2 ca[32];
    ca[0] = pf;
    #pragma unroll
    for (int bp = 0; bp < 5; ++bp) {
        const float* vq = vt + (5 - bp) * 4;
        float2 v0 = make_float2(vq[0], vq[1]), v1 = make_float2(vq[2], vq[3]);
        #pragma unroll
        for (int i = (1 << bp) - 1; i >= 0; --i) {
            float2 base = ca[i];
            ca[i + (1 << bp)] = cmulf(base, v1);
            ca[i] = cmulf(base, v0);
        }
    }
    float a[64];
    {
        const float* vq = vt;              // bp=5 <-> x bit 17 <-> qubit 0
        float2 v0 = make_float2(vq[0], vq[1]), v1 = make_float2(vq[2], vq[3]);
        #pragma unroll
        for (int i = 0; i < 32; ++i) {     // real part only from here on
            a[i]      = ca[i].x * v0.x - ca[i].y * v0.y;
            a[i + 32] = ca[i].x * v1.x - ca[i].y * v1.y;
        }
    }
    apply_gates<12, 0, 12, 64>(a, xf0, csn);

    // ph0 write: y = (j<<8)|t, j = q*8+r.  slot = [St ^ r*260] + q*2048 (additive!)
    unsigned St = (unsigned)t ^ ((unsigned)t >> 6);
    unroll<8>([&](auto Rr) {
        constexpr int r = Rr.value;
        unsigned br = St ^ (unsigned)((r << 8) | (r << 2));
        unroll<8>([&](auto Qq) {
            constexpr int q = Qq.value;
            lds[br + (q << 11)] = a[q * 8 + r];
        });
    });
    __syncthreads();

    // ph1: y = base1 | (j<<6); slot(base1) = base1; K = (j<<6)|(j&31)
    unsigned Sb1 = (unsigned)(t & 63) | ((unsigned)(t >> 6) << 12);
    unroll<64>([&](auto J) {
        constexpr unsigned K = (unsigned)((J.value << 6) | (J.value & 31));
        a[J.value] = lds[Sb1 ^ K];
    });
    unsigned xf1 = (unsigned)c4 | ((unsigned)(t & 63) << 4) | ((unsigned)(t >> 6) << 16);
    apply_gates<10, 12, 6, 64>(a, xf1, csn);
    unroll<64>([&](auto J) {
        constexpr unsigned K = (unsigned)((J.value << 6) | (J.value & 31));
        lds[Sb1 ^ K] = a[J.value];
    });
    __syncthreads();

    // ph2: y = base2 | (j<<3); slot(base2) = base2 ^ ((t>>3)&3)<<3; K = (j<<3)|(j>>3)
    unsigned Sb2 = ((unsigned)(t & 7) | ((unsigned)(t >> 3) << 9))
                 ^ ((((unsigned)t >> 3) & 3u) << 3);
    unroll<64>([&](auto J) {
        constexpr unsigned K = (unsigned)((J.value << 3) | (J.value >> 3));
        a[J.value] = lds[Sb2 ^ K];
    });
    unsigned xf2 = (unsigned)c4 | ((unsigned)(t & 7) << 4) | ((unsigned)(t >> 3) << 13);
    apply_gates<7, 18, 9, 64>(a, xf2, csn);
    unroll<64>([&](auto J) {
        constexpr unsigned K = (unsigned)((J.value << 3) | (J.value >> 3));
        lds[Sb2 ^ K] = a[J.value];
    });
    __syncthreads();

    // ph3: y = j | (t<<6); slot(t<<6) = (t<<6)^(t&31); addr = Sb3 ^ j
    unsigned Sb3 = ((unsigned)t << 6) ^ ((unsigned)t & 31u);
    unroll<64>([&](auto J) {
        a[J.value] = lds[Sb3 ^ (unsigned)J.value];
    });
    unsigned xf3 = (unsigned)c4 | ((unsigned)t << 10);
    apply_gates<4, 27, 9, 64>(a, xf3, csn);

    // direct stores: offset = (t&63) | (j>>3)<<6 | c4<<9 | (j&7)<<13 | (t>>6)<<16 | b<<18
    float* wp = ws + (((size_t)b << 18) | ((size_t)(t >> 6) << 16)
                      | ((size_t)c4 << 9) | (size_t)(t & 63));
    unroll<64>([&](auto J) {
        constexpr int j = J.value;
        constexpr unsigned off = (unsigned)(((j >> 3) << 6) | ((j & 7) << 13));
        wp[off] = a[j];
    });
}

// pass B: output-major. Thread m owns out floats s = m<<7 | d (contiguous 512B).
// Reads A[x], x0..6 free, x7..17 = M = m^(m>>4). 18 gates on x bits 0..6.
// Store via 32 KiB LDS quarter-staging (4 rounds, writer = one wave/round):
//   logical z = w6<<7 | d (13b); phys = z ^ ((w6<<1)&28).
//   writer quad: D = (n0^cc)^((n0^cc)>>4); phys base = Sw ^ (D&~3); perm4 by D&3.
//   reader: straight copy, store addr z0 = p0 ^ ((p0>>6)&28) (lane-contiguous lines).
__global__ __launch_bounds__(256, 3) void k_passB(const float* __restrict__ ws,
                                                  float* __restrict__ out) {
    __shared__ __align__(16) float lds[8192];    // 32 KiB
    const int t = threadIdx.x;
    const int b = blockIdx.x >> 3;               // 8 blocks per sample
    const int m = ((blockIdx.x & 7) << 8) | t;   // [0, 2048)
    const float* csn = ws + CS_OFFC;
    unsigned Mv = (unsigned)m ^ ((unsigned)m >> 4); // x bits 7..17

    const float* rb = ws + (((size_t)b << 18)
                    | (size_t)((Mv >> 3) & 7u)
                    | ((size_t)((Mv >> 6) & 7u) << 3)
                    | ((size_t)(Mv & 7u) << 6)
                    | ((size_t)((Mv >> 9) & 3u) << 16));
    float a[128];
    unroll<128>([&](auto N) {
        constexpr int n = N.value;
        constexpr unsigned off = (unsigned)(((n & 15) << 9) | ((n >> 4) << 13));
        a[n] = rb[off];
    });
    apply_gates<0, 36, 18, 128>(a, Mv << 7, csn);

    unsigned cc = ((unsigned)m & 15u) << 3;
    float* obb = out + (((size_t)b << NQ) | ((size_t)(blockIdx.x & 7) << 15));
    const unsigned w6 = (unsigned)(t & 63);
    const unsigned Sw = (w6 << 7) ^ ((w6 << 1) & 28u);
    const int myQ = t >> 6;
    #pragma unroll
    for (int Q = 0; Q < 4; ++Q) {
        if (myQ == Q) {
            unroll<32>([&](auto Qd) {
                constexpr int n0 = Qd.value << 2;
                unsigned nx = (unsigned)n0 ^ cc;
                unsigned D  = (nx ^ (nx >> 4)) & 127u;
                unsigned Bq = Sw ^ (D & ~3u);
                float4 v = make_float4(a[n0], a[n0 ^ 1], a[n0 ^ 2], a[n0 ^ 3]);
                *(float4*)&lds[Bq] = perm4(v, (int)(D & 3u));
            });
        }
        __syncthreads();
        float* ohQ = obb + ((size_t)Q << 13);
        unroll<8>([&](auto I) {
            constexpr int i = I.value;
            unsigned p0 = ((unsigned)(i * 256) + (unsigned)t) << 2;
            unsigned z0 = p0 ^ ((p0 >> 6) & 28u);
            *(float4*)&ohQ[z0] = *(const float4*)&lds[p0];
        });
        __syncthreads();
    }
}

// ======================= fallback (proven R5 path, no ws) =======================
__global__ __launch_bounds__(256) void k_init_f(const float* __restrict__ inputs,
                                                const float* __restrict__ params,
                                                float* __restrict__ S) {
    __shared__ float2 vt[2][NQ];
    int g = blockIdx.x * 256 + threadIdx.x;
    int b = g >> 13;
    int t = threadIdx.x;
    if (t < NQ) {
        float x = 0.5f * inputs[b * NQ + t];
        float cx = cosf(x), sx = sinf(x);
        float th = 0.5f * params[t];
        float c = cosf(th), s = sinf(th);
        vt[0][t] = make_float2(c * cx,  s * sx);
        vt[1][t] = make_float2(s * cx, -c * sx);
    }
    __syncthreads();
    unsigned OW = (unsigned)(g & 0x1FFF);
    unsigned iu = OW ^ (OW >> 1);
    int pu = OW & 1;
    float2 p = make_float2(1.f, 0.f);
    #pragma unroll
    for (int q = 0; q <= 12; ++q) {
        int bit = (iu >> (12 - q)) & 1;
        p = cmulf(p, vt[bit][q]);
    }
    float2 a[32];
    a[0] = p;
    #pragma unroll
    for (int bp = 0; bp < 5; ++bp) {
        float2 v0 = vt[0][17 - bp], v1 = vt[1][17 - bp];
        if (bp == 4 && pu) { float2 tt = v0; v0 = v1; v1 = tt; }
        #pragma unroll
        for (int i = (1 << bp) - 1; i >= 0; --i) {
            float2 base = a[i];
            a[i + (1 << bp)] = cmulf(base, v1);
            a[i] = cmulf(base, v0);
        }
    }
    float* outp = S + ((size_t)b << NQ) + ((size_t)OW << 5);
    #pragma unroll
    for (int oj = 0; oj < 32; oj += 4) {
        int k0 = oj ^ (oj >> 1);
        *(float4*)(outp + oj) = make_float4(a[k0].x, a[k0 ^ 1].x, a[k0 ^ 3].x, a[k0 ^ 2].x);
    }
}

template<int P>
__global__ __launch_bounds__(256) void k_pass_f(const float* __restrict__ params,
                                                float* __restrict__ S, int layer) {
    int g = blockIdx.x * 256 + threadIdx.x;
    float cg[6], sg[6];
    #pragma unroll
    for (int i = 0; i < 6; ++i) {
        float th = 0.5f * params[layer * NQ + 6 * P + i];
        cg[i] = cosf(th); sg[i] = sinf(th);
    }
    size_t base; int hm;
    constexpr int STR = (P == 0) ? 4096 : (P == 1) ? 64 : 1;
    if constexpr (P == 0) {
        base = ((size_t)(g >> 12) << NQ) | (size_t)(g & 0xFFF);
        hm = 0;
    } else if constexpr (P == 1) {
        base = ((size_t)(g >> 12) << NQ) | ((size_t)((g >> 6) & 63) << 12) | (size_t)(g & 63);
        hm = (g >> 6) & 1;
    } else {
        base = (size_t)g << 6;
        hm = g & 1;
    }
    float a[64];
    if constexpr (P == 2) {
        #pragma unroll
        for (int j = 0; j < 64; j += 4) {
            float4 w = *(const float4*)(S + base + j);
            a[j] = w.x; a[j + 1] = w.y; a[j + 2] = w.z; a[j + 3] = w.w;
        }
    } else {
        #pragma unroll
        for (int j = 0; j < 64; ++j) a[j] = S[base + (size_t)j * STR];
    }
    #pragma unroll
    for (int i = 0; i < 6; ++i) {
        int mm = 32 >> i;
        #pragma unroll
        for (int r = 0; r < 64; ++r) if (!(r & mm)) {
            float x0 = a[r], x1 = a[r | mm];
            a[r]      = cg[i] * x0 - sg[i] * x1;
            a[r | mm] = sg[i] * x0 + cg[i] * x1;
        }
    }
    if (hm) {
        #pragma unroll
        for (int r = 0; r < 32; ++r) { float tt = a[r]; a[r] = a[r ^ 32]; a[r ^ 32] = tt; }
    }
    if constexpr (P == 2) {
        #pragma unroll
        for (int oj = 0; oj < 64; oj += 4) {
            int k0 = oj ^ (oj >> 1);
            *(float4*)(S + base + oj) = make_float4(a[k0], a[k0 ^ 1], a[k0 ^ 3], a[k0 ^ 2]);
        }
    } else {
        #pragma unroll
        for (int oj = 0; oj < 64; ++oj)
            S[base + (size_t)oj * STR] = a[oj ^ (oj >> 1)];
    }
}

extern "C" void kernel_launch(void* const* d_in, const int* in_sizes, int n_in,
                              void* d_out, int out_size, void* d_ws, size_t ws_size,
                              hipStream_t stream) {
    const float* inputs = (const float*)d_in[0];   // (64, 18) f32
    const float* params = (const float*)d_in[1];   // (4, 18, 1) f32
    float* out = (float*)d_out;                    // (64, 2^18) f32 = Re(state)
    float* ws  = (float*)d_ws;
    const size_t need = (size_t)4 * ((1ull << 24) + BATCH * NQ * 4 + 108);

    if (ws_size >= need) {
        k_prep<<<5, 256, 0, stream>>>(inputs, params, ws);
        k_passA<<<BATCH * 16, 256, 0, stream>>>(ws, ws);
        k_passB<<<512, 256, 0, stream>>>(ws, out);
    } else {
        k_init_f<<<2048, 256, 0, stream>>>(inputs, params, out);
        for (int layer = 1; layer < 4; ++layer) {
            k_pass_f<0><<<1024, 256, 0, stream>>>(params, out, layer);
            k_pass_f<1><<<1024, 256, 0, stream>>>(params, out, layer);
            k_pass_f<2><<<1024, 256, 0, stream>>>(params, out, layer);
        }
    }
}

// Round 11
// 80.964 us; speedup vs baseline: 1.3365x; 1.3365x over previous
//
#include <hip/hip_runtime.h>
#include <utility>

#define NQ 18
#define BATCH 64

// ws float-offsets for the fast path
#define VT_OFFC (1u << 24)                      // 64*2^18 state floats first
#define CS_OFFC (VT_OFFC + BATCH * NQ * 4)      // then vt table, then cos/sin table

__device__ __forceinline__ float2 cmulf(float2 a, float2 b) {
    return make_float2(a.x * b.x - a.y * b.y, a.x * b.y + a.y * b.x);
}

template<class F, int... Is>
__device__ __forceinline__ void unroll_impl(F f, std::integer_sequence<int, Is...>) {
    (f(std::integral_constant<int, Is>{}), ...);
}
template<int N, class F>
__device__ __forceinline__ void unroll(F f) {
    unroll_impl(f, std::make_integer_sequence<int, N>{});
}

// ---------------------------------------------------------------------------
// Gate algebra (storage order fixed = logical order at layer 1):
//  ladder = linear map T: s -> s ^ (s>>1)  (final[s] = pre[T s])
//  layer-k RY(qubit q), p = 17-q, conjugated to stored coords:
//    mask m = T^(k-1) e_p ; orientation O = row p of T^-(k-1)
//  Output perm: out[s] = A[T^4 s], T^4 s = s ^ (s>>4).
//
// Inter-pass ws layout: float offset = (x10..15) | (x7..9)<<6 | (x0..3)<<9
//                     | (x4..6)<<13 | (x16..17)<<16 | b<<18
// LDS tile swizzle slot(y) = y ^ ((y>>6)&31) is GF(2)-LINEAR -> per-phase
// addresses hoist to  slot(P_t) ^ slot(K_j)  (runtime base ^ compile-time K).
// ---------------------------------------------------------------------------
struct Gate { int k, p; };
constexpr Gate GT[54] = {
    // pass A phase 0, window x 12..17
    {2,13},{2,14},{2,15},{2,16},{2,17}, {3,14},{3,15},{3,16},{3,17}, {4,15},{4,16},{4,17},
    // phase 1, window x 10..15
    {2,11},{2,12}, {3,12},{3,13}, {4,13},{4,14},
    // phase 2, window x 7..12
    {2,8},{2,9},{2,10}, {3,9},{3,10},{3,11}, {4,10},{4,11},{4,12},
    // phase 3, window x 4..9
    {2,5},{2,6},{2,7}, {3,6},{3,7},{3,8}, {4,7},{4,8},{4,9},
    // pass B, window x 0..6
    {2,0},{2,1},{2,2},{2,3},{2,4},
    {3,0},{3,1},{3,2},{3,3},{3,4},{3,5},
    {4,0},{4,1},{4,2},{4,3},{4,4},{4,5},{4,6},
};
constexpr unsigned gmask(Gate g) {
    return g.k == 2 ? (g.p >= 1 ? 3u << (g.p - 1) : 1u)
         : g.k == 3 ? (g.p >= 2 ? 5u << (g.p - 2) : 1u << g.p)
         : (g.p >= 3 ? 15u << (g.p - 3) : (1u << (g.p + 1)) - 1u);
}
constexpr unsigned gorient(Gate g) {
    return g.k == 2 ? (0x3FFFFu & ~((1u << g.p) - 1u))
         : g.k == 3 ? ((0x15555u << g.p) & 0x3FFFFu)
         : ((0x33333u << g.p) & 0x3FFFFu);
}
constexpr int gcsi(Gate g) { return (g.k - 2) * NQ + (17 - g.p); }

// Apply NG gates (GT[OFF..OFF+NG)) on NR=2^w register window starting at x-bit WL.
template<int WL, int OFF, int NG, int NR>
__device__ __forceinline__ void apply_gates(float* a, unsigned xfix, const float* csn) {
    unroll<NG>([&](auto I) {
        constexpr Gate g = GT[OFF + I.value];
        constexpr unsigned m  = gmask(g);
        constexpr unsigned O  = gorient(g);
        constexpr unsigned mr = (m >> WL) & (unsigned)(NR - 1);
        constexpr unsigned hb = 1u << (g.p - WL);
        constexpr unsigned Or = (O >> WL) & (unsigned)(NR - 1);
        constexpr unsigned Of = O & ~(((unsigned)(NR - 1)) << WL);
        float c = csn[2 * gcsi(g)], s = csn[2 * gcsi(g) + 1];
        float ps = (__popc(xfix & Of) & 1) ? -s : s;
        float ms = -ps;
        unroll<NR>([&](auto R) {
            constexpr int r = R.value;
            if constexpr ((r & (int)hb) == 0) {
                constexpr int r2 = r ^ (int)mr;
                constexpr bool fl = (__builtin_popcount((unsigned)r & Or) & 1) != 0;
                float se = fl ? ms : ps;
                float x0 = a[r], x1 = a[r2];
                a[r]  = c * x0 - se * x1;
                a[r2] = se * x0 + c * x1;
            }
        });
    });
}

// component unpermute by XOR k (k in 0..3): t_c <- r_{c^k}
__device__ __forceinline__ float4 perm4(float4 r, int k) {
    float t0 = r.x, t1 = r.y, t2 = r.z, t3 = r.w;
    if (k & 1) { float x; x=t0;t0=t1;t1=x; x=t2;t2=t3;t3=x; }
    if (k & 2) { float x; x=t0;t0=t2;t2=x; x=t1;t1=t3;t3=x; }
    return make_float4(t0, t1, t2, t3);
}

// prep: vt[b][q] = RY(p0q/2)*RX(x/2)|0> (4 floats), plus cos/sin for layers 1..3
__global__ void k_prep(const float* __restrict__ inputs, const float* __restrict__ params,
                       float* __restrict__ ws) {
    int t = blockIdx.x * blockDim.x + threadIdx.x;
    if (t < BATCH * NQ) {
        int q = t % NQ;
        float x = 0.5f * inputs[t];
        float cx = cosf(x), sx = sinf(x);
        float th = 0.5f * params[q];
        float c = cosf(th), s = sinf(th);
        float* v = ws + VT_OFFC + t * 4;
        v[0] = c * cx;  v[1] = s * sx;     // v0 = c*cx + i*s*sx
        v[2] = s * cx;  v[3] = -c * sx;    // v1 = s*cx - i*c*sx
    } else if (t < BATCH * NQ + 54) {
        int i = t - BATCH * NQ;            // (k-2)*18 + q  -> params[(k-1)*18+q]
        float th = 0.5f * params[NQ + i];
        ws[CS_OFFC + 2 * i]     = cosf(th);
        ws[CS_OFFC + 2 * i + 1] = sinf(th);
    }
}

// pass A: init product (layer 0 folded) + 36 gates on x bits 4..17.
// WG = (b, c4 = x bits 0..3); tile = 2^14 f32 in LDS (4 gate phases).
// All LDS addresses hoisted: slot(P|K) = slot(P) ^ slot(K) (GF2-linear).
__global__ __launch_bounds__(256) void k_passA(const float* __restrict__ ws_tab,
                                               float* __restrict__ ws) {
    __shared__ __align__(16) float lds[16384];   // exactly 64 KiB
    const int b  = blockIdx.x >> 4;
    const int c4 = blockIdx.x & 15;
    const int t  = threadIdx.x;
    const float* vt  = ws_tab + VT_OFFC + b * NQ * 4;
    const float* csn = ws_tab + CS_OFFC;

    // init: complex product, reg bit bp <-> x bit 12+bp <-> qubit 5-bp
    unsigned xf0 = (unsigned)c4 | ((unsigned)t << 4);   // x bits 0..11
    float2 pf = make_float2(1.f, 0.f);
    #pragma unroll
    for (int i = 0; i < 12; ++i) {
        int bit = (xf0 >> i) & 1;
        const float* vq = vt + (17 - i) * 4 + bit * 2;
        pf = cmulf(pf, make_float2(vq[0], vq[1]));
    }
    float2 ca[32];
    ca[0] = pf;
    #pragma unroll
    for (int bp = 0; bp < 5; ++bp) {
        const float* vq = vt + (5 - bp) * 4;
        float2 v0 = make_float2(vq[0], vq[1]), v1 = make_float2(vq[2], vq[3]);
        #pragma unroll
        for (int i = (1 << bp) - 1; i >= 0; --i) {
            float2 base = ca[i];
            ca[i + (1 << bp)] = cmulf(base, v1);
            ca[i] = cmulf(base, v0);
        }
    }
    float a[64];
    {
        const float* vq = vt;              // bp=5 <-> x bit 17 <-> qubit 0
        float2 v0 = make_float2(vq[0], vq[1]), v1 = make_float2(vq[2], vq[3]);
        #pragma unroll
        for (int i = 0; i < 32; ++i) {     // real part only from here on
            a[i]      = ca[i].x * v0.x - ca[i].y * v0.y;
            a[i + 32] = ca[i].x * v1.x - ca[i].y * v1.y;
        }
    }
    apply_gates<12, 0, 12, 64>(a, xf0, csn);

    // ph0 write: y = (j<<8)|t, j = q*8+r.  slot = [St ^ r*260] + q*2048 (additive!)
    unsigned St = (unsigned)t ^ ((unsigned)t >> 6);
    unroll<8>([&](auto Rr) {
        constexpr int r = Rr.value;
        unsigned br = St ^ (unsigned)((r << 8) | (r << 2));
        unroll<8>([&](auto Qq) {
            constexpr int q = Qq.value;
            lds[br + (q << 11)] = a[q * 8 + r];
        });
    });
    __syncthreads();

    // ph1: y = base1 | (j<<6); slot(base1) = base1; K = (j<<6)|(j&31)
    unsigned Sb1 = (unsigned)(t & 63) | ((unsigned)(t >> 6) << 12);
    unroll<64>([&](auto J) {
        constexpr unsigned K = (unsigned)((J.value << 6) | (J.value & 31));
        a[J.value] = lds[Sb1 ^ K];
    });
    unsigned xf1 = (unsigned)c4 | ((unsigned)(t & 63) << 4) | ((unsigned)(t >> 6) << 16);
    apply_gates<10, 12, 6, 64>(a, xf1, csn);
    unroll<64>([&](auto J) {
        constexpr unsigned K = (unsigned)((J.value << 6) | (J.value & 31));
        lds[Sb1 ^ K] = a[J.value];
    });
    __syncthreads();

    // ph2: y = base2 | (j<<3); slot(base2) = base2 ^ ((t>>3)&3)<<3; K = (j<<3)|(j>>3)
    unsigned Sb2 = ((unsigned)(t & 7) | ((unsigned)(t >> 3) << 9))
                 ^ ((((unsigned)t >> 3) & 3u) << 3);
    unroll<64>([&](auto J) {
        constexpr unsigned K = (unsigned)((J.value << 3) | (J.value >> 3));
        a[J.value] = lds[Sb2 ^ K];
    });
    unsigned xf2 = (unsigned)c4 | ((unsigned)(t & 7) << 4) | ((unsigned)(t >> 3) << 13);
    apply_gates<7, 18, 9, 64>(a, xf2, csn);
    unroll<64>([&](auto J) {
        constexpr unsigned K = (unsigned)((J.value << 3) | (J.value >> 3));
        lds[Sb2 ^ K] = a[J.value];
    });
    __syncthreads();

    // ph3: y = j | (t<<6); slot(t<<6) = (t<<6)^(t&31); addr = Sb3 ^ j
    unsigned Sb3 = ((unsigned)t << 6) ^ ((unsigned)t & 31u);
    unroll<64>([&](auto J) {
        a[J.value] = lds[Sb3 ^ (unsigned)J.value];
    });
    unsigned xf3 = (unsigned)c4 | ((unsigned)t << 10);
    apply_gates<4, 27, 9, 64>(a, xf3, csn);

    // direct stores: offset = (t&63) | (j>>3)<<6 | c4<<9 | (j&7)<<13 | (t>>6)<<16 | b<<18
    float* wp = ws + (((size_t)b << 18) | ((size_t)(t >> 6) << 16)
                      | ((size_t)c4 << 9) | (size_t)(t & 63));
    unroll<64>([&](auto J) {
        constexpr int j = J.value;
        constexpr unsigned off = (unsigned)(((j >> 3) << 6) | ((j & 7) << 13));
        wp[off] = a[j];
    });
}

// pass B: output-major. Thread m owns out floats s = m<<7 | d (contiguous 512B).
// Reads A[x], x0..6 free, x7..17 = M = m^(m>>4). 18 gates on x bits 0..6.
// Store via 32 KiB LDS quarter-staging (4 rounds, writer = one wave/round).
// NOTE: plain launch_bounds(256) — the (256,3) variant spilled a[128] to
// scratch (R10: VGPR=84, WRITE 163MB, dur +70%). Do not cap VGPRs here.
__global__ __launch_bounds__(256) void k_passB(const float* __restrict__ ws,
                                               float* __restrict__ out) {
    __shared__ __align__(16) float lds[8192];    // 32 KiB
    const int t = threadIdx.x;
    const int b = blockIdx.x >> 3;               // 8 blocks per sample
    const int m = ((blockIdx.x & 7) << 8) | t;   // [0, 2048)
    const float* csn = ws + CS_OFFC;
    unsigned Mv = (unsigned)m ^ ((unsigned)m >> 4); // x bits 7..17

    const float* rb = ws + (((size_t)b << 18)
                    | (size_t)((Mv >> 3) & 7u)
                    | ((size_t)((Mv >> 6) & 7u) << 3)
                    | ((size_t)(Mv & 7u) << 6)
                    | ((size_t)((Mv >> 9) & 3u) << 16));
    float a[128];
    unroll<128>([&](auto N) {
        constexpr int n = N.value;
        constexpr unsigned off = (unsigned)(((n & 15) << 9) | ((n >> 4) << 13));
        a[n] = rb[off];
    });
    apply_gates<0, 36, 18, 128>(a, Mv << 7, csn);

    unsigned cc = ((unsigned)m & 15u) << 3;
    float* obb = out + (((size_t)b << NQ) | ((size_t)(blockIdx.x & 7) << 15));
    const unsigned w6 = (unsigned)(t & 63);
    const unsigned Sw = (w6 << 7) ^ ((w6 << 1) & 28u);
    const int myQ = t >> 6;
    #pragma unroll
    for (int Q = 0; Q < 4; ++Q) {
        if (myQ == Q) {
            unroll<32>([&](auto Qd) {
                constexpr int n0 = Qd.value << 2;
                unsigned nx = (unsigned)n0 ^ cc;
                unsigned D  = (nx ^ (nx >> 4)) & 127u;
                unsigned Bq = Sw ^ (D & ~3u);
                float4 v = make_float4(a[n0], a[n0 ^ 1], a[n0 ^ 2], a[n0 ^ 3]);
                *(float4*)&lds[Bq] = perm4(v, (int)(D & 3u));
            });
        }
        __syncthreads();
        float* ohQ = obb + ((size_t)Q << 13);
        unroll<8>([&](auto I) {
            constexpr int i = I.value;
            unsigned p0 = ((unsigned)(i * 256) + (unsigned)t) << 2;
            unsigned z0 = p0 ^ ((p0 >> 6) & 28u);
            *(float4*)&ohQ[z0] = *(const float4*)&lds[p0];
        });
        __syncthreads();
    }
}

// ======================= fallback (proven R5 path, no ws) =======================
__global__ __launch_bounds__(256) void k_init_f(const float* __restrict__ inputs,
                                                const float* __restrict__ params,
                                                float* __restrict__ S) {
    __shared__ float2 vt[2][NQ];
    int g = blockIdx.x * 256 + threadIdx.x;
    int b = g >> 13;
    int t = threadIdx.x;
    if (t < NQ) {
        float x = 0.5f * inputs[b * NQ + t];
        float cx = cosf(x), sx = sinf(x);
        float th = 0.5f * params[t];
        float c = cosf(th), s = sinf(th);
        vt[0][t] = make_float2(c * cx,  s * sx);
        vt[1][t] = make_float2(s * cx, -c * sx);
    }
    __syncthreads();
    unsigned OW = (unsigned)(g & 0x1FFF);
    unsigned iu = OW ^ (OW >> 1);
    int pu = OW & 1;
    float2 p = make_float2(1.f, 0.f);
    #pragma unroll
    for (int q = 0; q <= 12; ++q) {
        int bit = (iu >> (12 - q)) & 1;
        p = cmulf(p, vt[bit][q]);
    }
    float2 a[32];
    a[0] = p;
    #pragma unroll
    for (int bp = 0; bp < 5; ++bp) {
        float2 v0 = vt[0][17 - bp], v1 = vt[1][17 - bp];
        if (bp == 4 && pu) { float2 tt = v0; v0 = v1; v1 = tt; }
        #pragma unroll
        for (int i = (1 << bp) - 1; i >= 0; --i) {
            float2 base = a[i];
            a[i + (1 << bp)] = cmulf(base, v1);
            a[i] = cmulf(base, v0);
        }
    }
    float* outp = S + ((size_t)b << NQ) + ((size_t)OW << 5);
    #pragma unroll
    for (int oj = 0; oj < 32; oj += 4) {
        int k0 = oj ^ (oj >> 1);
        *(float4*)(outp + oj) = make_float4(a[k0].x, a[k0 ^ 1].x, a[k0 ^ 3].x, a[k0 ^ 2].x);
    }
}

template<int P>
__global__ __launch_bounds__(256) void k_pass_f(const float* __restrict__ params,
                                                float* __restrict__ S, int layer) {
    int g = blockIdx.x * 256 + threadIdx.x;
    float cg[6], sg[6];
    #pragma unroll
    for (int i = 0; i < 6; ++i) {
        float th = 0.5f * params[layer * NQ + 6 * P + i];
        cg[i] = cosf(th); sg[i] = sinf(th);
    }
    size_t base; int hm;
    constexpr int STR = (P == 0) ? 4096 : (P == 1) ? 64 : 1;
    if constexpr (P == 0) {
        base = ((size_t)(g >> 12) << NQ) | (size_t)(g & 0xFFF);
        hm = 0;
    } else if constexpr (P == 1) {
        base = ((size_t)(g >> 12) << NQ) | ((size_t)((g >> 6) & 63) << 12) | (size_t)(g & 63);
        hm = (g >> 6) & 1;
    } else {
        base = (size_t)g << 6;
        hm = g & 1;
    }
    float a[64];
    if constexpr (P == 2) {
        #pragma unroll
        for (int j = 0; j < 64; j += 4) {
            float4 w = *(const float4*)(S + base + j);
            a[j] = w.x; a[j + 1] = w.y; a[j + 2] = w.z; a[j + 3] = w.w;
        }
    } else {
        #pragma unroll
        for (int j = 0; j < 64; ++j) a[j] = S[base + (size_t)j * STR];
    }
    #pragma unroll
    for (int i = 0; i < 6; ++i) {
        int mm = 32 >> i;
        #pragma unroll
        for (int r = 0; r < 64; ++r) if (!(r & mm)) {
            float x0 = a[r], x1 = a[r | mm];
            a[r]      = cg[i] * x0 - sg[i] * x1;
            a[r | mm] = sg[i] * x0 + cg[i] * x1;
        }
    }
    if (hm) {
        #pragma unroll
        for (int r = 0; r < 32; ++r) { float tt = a[r]; a[r] = a[r ^ 32]; a[r ^ 32] = tt; }
    }
    if constexpr (P == 2) {
        #pragma unroll
        for (int oj = 0; oj < 64; oj += 4) {
            int k0 = oj ^ (oj >> 1);
            *(float4*)(S + base + oj) = make_float4(a[k0], a[k0 ^ 1], a[k0 ^ 3], a[k0 ^ 2]);
        }
    } else {
        #pragma unroll
        for (int oj = 0; oj < 64; ++oj)
            S[base + (size_t)oj * STR] = a[oj ^ (oj >> 1)];
    }
}

extern "C" void kernel_launch(void* const* d_in, const int* in_sizes, int n_in,
                              void* d_out, int out_size, void* d_ws, size_t ws_size,
                              hipStream_t stream) {
    const float* inputs = (const float*)d_in[0];   // (64, 18) f32
    const float* params = (const float*)d_in[1];   // (4, 18, 1) f32
    float* out = (float*)d_out;                    // (64, 2^18) f32 = Re(state)
    float* ws  = (float*)d_ws;
    const size_t need = (size_t)4 * ((1ull << 24) + BATCH * NQ * 4 + 108);

    if (ws_size >= need) {
        k_prep<<<5, 256, 0, stream>>>(inputs, params, ws);
        k_passA<<<BATCH * 16, 256, 0, stream>>>(ws, ws);
        k_passB<<<512, 256, 0, stream>>>(ws, out);
    } else {
        k_init_f<<<2048, 256, 0, stream>>>(inputs, params, out);
        for (int layer = 1; layer < 4; ++layer) {
            k_pass_f<0><<<1024, 256, 0, stream>>>(params, out, layer);
            k_pass_f<1><<<1024, 256, 0, stream>>>(params, out, layer);
            k_pass_f<2><<<1024, 256, 0, stream>>>(params, out, layer);
        }
    }
}

// Round 12
// 76.582 us; speedup vs baseline: 1.4130x; 1.0572x over previous
//
#include <hip/hip_runtime.h>
#include <utility>

#define NQ 18
#define BATCH 64

// ws float-offsets for the fast path
#define VT_OFFC (1u << 24)                      // 64*2^18 state floats first
#define CS_OFFC (VT_OFFC + BATCH * NQ * 4)      // then vt table, then cos/sin table

typedef float v2f __attribute__((ext_vector_type(2)));

__device__ __forceinline__ float2 cmulf(float2 a, float2 b) {
    return make_float2(a.x * b.x - a.y * b.y, a.x * b.y + a.y * b.x);
}

template<class F, int... Is>
__device__ __forceinline__ void unroll_impl(F f, std::integer_sequence<int, Is...>) {
    (f(std::integral_constant<int, Is>{}), ...);
}
template<int N, class F>
__device__ __forceinline__ void unroll(F f) {
    unroll_impl(f, std::make_integer_sequence<int, N>{});
}

// ---------------------------------------------------------------------------
// Gate algebra (storage order fixed = logical order at layer 1):
//  ladder = linear map T: s -> s ^ (s>>1)  (final[s] = pre[T s])
//  layer-k RY(qubit q), p = 17-q, conjugated to stored coords:
//    mask m = T^(k-1) e_p ; orientation O = row p of T^-(k-1)
//  Output perm: out[s] = A[T^4 s], T^4 s = s ^ (s>>4).
//
// Inter-pass ws layout: float offset = (x10..15) | (x7..9)<<6 | (x0..3)<<9
//                     | (x4..6)<<13 | (x16..17)<<16 | b<<18
// LDS tile swizzle slot(y) = y ^ ((y>>6)&31) is GF(2)-LINEAR -> per-phase
// addresses hoist to  slot(P_t) ^ slot(K_j)  (runtime base ^ compile-time K).
//
// Registers are PACKED as v2f: A[R] holds scalar amps (2R, 2R+1); vertical
// gates (mask bit0 clear) use v_pk_fma_f32-shaped vector ops.
// ---------------------------------------------------------------------------
struct Gate { int k, p; };
constexpr Gate GT[54] = {
    // pass A phase 0, window x 12..17
    {2,13},{2,14},{2,15},{2,16},{2,17}, {3,14},{3,15},{3,16},{3,17}, {4,15},{4,16},{4,17},
    // phase 1, window x 10..15
    {2,11},{2,12}, {3,12},{3,13}, {4,13},{4,14},
    // phase 2, window x 7..12
    {2,8},{2,9},{2,10}, {3,9},{3,10},{3,11}, {4,10},{4,11},{4,12},
    // phase 3, window x 4..9
    {2,5},{2,6},{2,7}, {3,6},{3,7},{3,8}, {4,7},{4,8},{4,9},
    // pass B, window x 0..6
    {2,0},{2,1},{2,2},{2,3},{2,4},
    {3,0},{3,1},{3,2},{3,3},{3,4},{3,5},
    {4,0},{4,1},{4,2},{4,3},{4,4},{4,5},{4,6},
};
constexpr unsigned gmask(Gate g) {
    return g.k == 2 ? (g.p >= 1 ? 3u << (g.p - 1) : 1u)
         : g.k == 3 ? (g.p >= 2 ? 5u << (g.p - 2) : 1u << g.p)
         : (g.p >= 3 ? 15u << (g.p - 3) : (1u << (g.p + 1)) - 1u);
}
constexpr unsigned gorient(Gate g) {
    return g.k == 2 ? (0x3FFFFu & ~((1u << g.p) - 1u))
         : g.k == 3 ? ((0x15555u << g.p) & 0x3FFFFu)
         : ((0x33333u << g.p) & 0x3FFFFu);
}
constexpr int gcsi(Gate g) { return (g.k - 2) * NQ + (17 - g.p); }

// Packed apply: NG gates on NR scalar regs held as v2f A[NR/2], window at x-bit WL.
// Scalar reg index r <-> (R = r>>1, comp = r&1). Pair signs: se(r) = ±ps with
// flip = popc(r & Or)&1; per-component split is compile-time via Or bit0.
template<int WL, int OFF, int NG, int NR>
__device__ __forceinline__ void apply_gates2(v2f* A, unsigned xfix, const float* csn) {
    constexpr int NR2 = NR / 2;
    unroll<NG>([&](auto I) {
        constexpr Gate g = GT[OFF + I.value];
        constexpr unsigned m   = gmask(g);
        constexpr unsigned O   = gorient(g);
        constexpr unsigned mr  = (m >> WL) & (unsigned)(NR - 1);
        constexpr unsigned hb  = 1u << (g.p - WL);
        constexpr unsigned Or  = (O >> WL) & (unsigned)(NR - 1);
        constexpr unsigned Of  = O & ~(((unsigned)(NR - 1)) << WL);
        constexpr unsigned Orf = Or >> 1;
        constexpr bool     Or0 = (Or & 1u) != 0;
        float c = csn[2 * gcsi(g)], s = csn[2 * gcsi(g) + 1];
        float psv = (__popc(xfix & Of) & 1) ? -s : s;
        float msv = -psv;
        v2f cv; cv.x = c; cv.y = c;
        if constexpr ((mr & 1u) == 0u) {
            // vertical: partner preserves component; fully packed
            constexpr unsigned hbf = hb >> 1, mrf = mr >> 1;
            unroll<NR2>([&](auto RR) {
                constexpr int R = RR.value;
                if constexpr ((R & (int)hbf) == 0) {
                    constexpr int R2 = R ^ (int)mrf;
                    constexpr bool fl0 = (__builtin_popcount((unsigned)R & Orf) & 1) != 0;
                    constexpr bool fl1 = fl0 != Or0;
                    v2f sev; sev.x = fl0 ? msv : psv; sev.y = fl1 ? msv : psv;
                    v2f x0 = A[R], x1 = A[R2];
                    A[R]  = cv * x0 - sev * x1;
                    A[R2] = sev * x0 + cv * x1;
                }
            });
        } else if constexpr (mr == 1u) {
            // pure horizontal: pair inside the v2f; se from low elem (bit0=0)
            unroll<NR2>([&](auto RR) {
                constexpr int R = RR.value;
                constexpr bool fl0 = (__builtin_popcount((unsigned)R & Orf) & 1) != 0;
                float se0 = fl0 ? msv : psv;
                v2f v = A[R], nv;
                nv.x = c * v.x - se0 * v.y;
                nv.y = se0 * v.x + c * v.y;
                A[R] = nv;
            });
        } else {
            // crossed: partner of (R,c) is (R^mrf, c^1); pair sign = se(low r)
            constexpr unsigned hbf = hb >> 1, mrf = mr >> 1;
            unroll<NR2>([&](auto RR) {
                constexpr int R = RR.value;
                if constexpr ((R & (int)hbf) == 0) {
                    constexpr int R2 = R ^ (int)mrf;
                    constexpr bool fl0 = (__builtin_popcount((unsigned)R & Orf) & 1) != 0;
                    constexpr bool fl1 = fl0 != Or0;
                    v2f sev; sev.x = fl0 ? msv : psv; sev.y = fl1 ? msv : psv;
                    v2f x0 = A[R], x1 = A[R2];
                    v2f x1s = __builtin_shufflevector(x1, x1, 1, 0);
                    v2f t   = sev * x0;
                    v2f ts  = __builtin_shufflevector(t, t, 1, 0);
                    A[R]  = cv * x0 - sev * x1s;
                    A[R2] = ts + cv * x1;
                }
            });
        }
    });
}

// scalar access helpers: a[j] == (j&1) ? A[j>>1].y : A[j>>1].x  (j compile-time)
template<int J>
__device__ __forceinline__ float geta(const v2f* A) {
    if constexpr (J & 1) return A[J >> 1].y; else return A[J >> 1].x;
}
template<int J>
__device__ __forceinline__ void seta(v2f* A, float v) {
    if constexpr (J & 1) A[J >> 1].y = v; else A[J >> 1].x = v;
}

// component unpermute by XOR k (k in 0..3): t_c <- r_{c^k}
__device__ __forceinline__ float4 perm4(float4 r, int k) {
    float t0 = r.x, t1 = r.y, t2 = r.z, t3 = r.w;
    if (k & 1) { float x; x=t0;t0=t1;t1=x; x=t2;t2=t3;t3=x; }
    if (k & 2) { float x; x=t0;t0=t2;t2=x; x=t1;t1=t3;t3=x; }
    return make_float4(t0, t1, t2, t3);
}

// prep: vt[b][q] = RY(p0q/2)*RX(x/2)|0> (4 floats), plus cos/sin for layers 1..3
__global__ void k_prep(const float* __restrict__ inputs, const float* __restrict__ params,
                       float* __restrict__ ws) {
    int t = blockIdx.x * blockDim.x + threadIdx.x;
    if (t < BATCH * NQ) {
        int q = t % NQ;
        float x = 0.5f * inputs[t];
        float cx = cosf(x), sx = sinf(x);
        float th = 0.5f * params[q];
        float c = cosf(th), s = sinf(th);
        float* v = ws + VT_OFFC + t * 4;
        v[0] = c * cx;  v[1] = s * sx;     // v0 = c*cx + i*s*sx
        v[2] = s * cx;  v[3] = -c * sx;    // v1 = s*cx - i*c*sx
    } else if (t < BATCH * NQ + 54) {
        int i = t - BATCH * NQ;            // (k-2)*18 + q  -> params[(k-1)*18+q]
        float th = 0.5f * params[NQ + i];
        ws[CS_OFFC + 2 * i]     = cosf(th);
        ws[CS_OFFC + 2 * i + 1] = sinf(th);
    }
}

// pass A: init product (layer 0 folded) + 36 gates on x bits 4..17.
// WG = (b, c4 = x bits 0..3); tile = 2^14 f32 in LDS (4 gate phases).
// All LDS addresses hoisted: slot(P|K) = slot(P) ^ slot(K) (GF2-linear).
__global__ __launch_bounds__(256) void k_passA(const float* __restrict__ ws_tab,
                                               float* __restrict__ ws) {
    __shared__ __align__(16) float lds[16384];   // exactly 64 KiB
    const int b  = blockIdx.x >> 4;
    const int c4 = blockIdx.x & 15;
    const int t  = threadIdx.x;
    const float* vt  = ws_tab + VT_OFFC + b * NQ * 4;
    const float* csn = ws_tab + CS_OFFC;

    // init: complex product, reg bit bp <-> x bit 12+bp <-> qubit 5-bp
    unsigned xf0 = (unsigned)c4 | ((unsigned)t << 4);   // x bits 0..11
    float2 pf = make_float2(1.f, 0.f);
    #pragma unroll
    for (int i = 0; i < 12; ++i) {
        int bit = (xf0 >> i) & 1;
        const float* vq = vt + (17 - i) * 4 + bit * 2;
        pf = cmulf(pf, make_float2(vq[0], vq[1]));
    }
    float2 ca[32];
    ca[0] = pf;
    #pragma unroll
    for (int bp = 0; bp < 5; ++bp) {
        const float* vq = vt + (5 - bp) * 4;
        float2 v0 = make_float2(vq[0], vq[1]), v1 = make_float2(vq[2], vq[3]);
        #pragma unroll
        for (int i = (1 << bp) - 1; i >= 0; --i) {
            float2 base = ca[i];
            ca[i + (1 << bp)] = cmulf(base, v1);
            ca[i] = cmulf(base, v0);
        }
    }
    v2f A[32];                             // scalar reg j: A[j>>1] comp j&1
    {
        const float* vq = vt;              // pack bit 5 <-> x bit 17 <-> qubit 0
        float2 v0 = make_float2(vq[0], vq[1]), v1 = make_float2(vq[2], vq[3]);
        unroll<16>([&](auto RR) {
            constexpr int R = RR.value;
            A[R].x      = ca[2*R].x   * v0.x - ca[2*R].y   * v0.y;
            A[R].y      = ca[2*R+1].x * v0.x - ca[2*R+1].y * v0.y;
            A[16+R].x   = ca[2*R].x   * v1.x - ca[2*R].y   * v1.y;
            A[16+R].y   = ca[2*R+1].x * v1.x - ca[2*R+1].y * v1.y;
        });
    }
    apply_gates2<12, 0, 12, 64>(A, xf0, csn);

    // ph0 write: y = (j<<8)|t, j = q*8+r.  slot = [St ^ r*260] + q*2048 (additive!)
    unsigned St = (unsigned)t ^ ((unsigned)t >> 6);
    unroll<8>([&](auto Rr) {
        constexpr int r = Rr.value;
        unsigned br = St ^ (unsigned)((r << 8) | (r << 2));
        unroll<8>([&](auto Qq) {
            constexpr int q = Qq.value;
            lds[br + (q << 11)] = geta<q * 8 + r>(A);
        });
    });
    __syncthreads();

    // ph1: y = base1 | (j<<6); slot(base1) = base1; K = (j<<6)|(j&31)
    unsigned Sb1 = (unsigned)(t & 63) | ((unsigned)(t >> 6) << 12);
    unroll<64>([&](auto J) {
        constexpr unsigned K = (unsigned)((J.value << 6) | (J.value & 31));
        seta<J.value>(A, lds[Sb1 ^ K]);
    });
    unsigned xf1 = (unsigned)c4 | ((unsigned)(t & 63) << 4) | ((unsigned)(t >> 6) << 16);
    apply_gates2<10, 12, 6, 64>(A, xf1, csn);
    unroll<64>([&](auto J) {
        constexpr unsigned K = (unsigned)((J.value << 6) | (J.value & 31));
        lds[Sb1 ^ K] = geta<J.value>(A);
    });
    __syncthreads();

    // ph2: y = base2 | (j<<3); slot(base2) = base2 ^ ((t>>3)&3)<<3; K = (j<<3)|(j>>3)
    unsigned Sb2 = ((unsigned)(t & 7) | ((unsigned)(t >> 3) << 9))
                 ^ ((((unsigned)t >> 3) & 3u) << 3);
    unroll<64>([&](auto J) {
        constexpr unsigned K = (unsigned)((J.value << 3) | (J.value >> 3));
        seta<J.value>(A, lds[Sb2 ^ K]);
    });
    unsigned xf2 = (unsigned)c4 | ((unsigned)(t & 7) << 4) | ((unsigned)(t >> 3) << 13);
    apply_gates2<7, 18, 9, 64>(A, xf2, csn);
    unroll<64>([&](auto J) {
        constexpr unsigned K = (unsigned)((J.value << 3) | (J.value >> 3));
        lds[Sb2 ^ K] = geta<J.value>(A);
    });
    __syncthreads();

    // ph3: y = j | (t<<6); slot(t<<6) = (t<<6)^(t&31); addr = Sb3 ^ j
    unsigned Sb3 = ((unsigned)t << 6) ^ ((unsigned)t & 31u);
    unroll<64>([&](auto J) {
        seta<J.value>(A, lds[Sb3 ^ (unsigned)J.value]);
    });
    unsigned xf3 = (unsigned)c4 | ((unsigned)t << 10);
    apply_gates2<4, 27, 9, 64>(A, xf3, csn);

    // direct stores: offset = (t&63) | (j>>3)<<6 | c4<<9 | (j&7)<<13 | (t>>6)<<16 | b<<18
    float* wp = ws + (((size_t)b << 18) | ((size_t)(t >> 6) << 16)
                      | ((size_t)c4 << 9) | (size_t)(t & 63));
    unroll<64>([&](auto J) {
        constexpr int j = J.value;
        constexpr unsigned off = (unsigned)(((j >> 3) << 6) | ((j & 7) << 13));
        wp[off] = geta<j>(A);
    });
}

// pass B: output-major. Thread m owns out floats s = m<<7 | d (contiguous 512B).
// Reads A[x], x0..6 free, x7..17 = M = m^(m>>4). 18 gates on x bits 0..6.
// Store via 32 KiB LDS quarter-staging (4 rounds, writer = one wave/round).
// NOTE: plain launch_bounds(256) — capping VGPRs spilled a[128] (R10).
__global__ __launch_bounds__(256) void k_passB(const float* __restrict__ ws,
                                               float* __restrict__ out) {
    __shared__ __align__(16) float lds[8192];    // 32 KiB
    const int t = threadIdx.x;
    const int b = blockIdx.x >> 3;               // 8 blocks per sample
    const int m = ((blockIdx.x & 7) << 8) | t;   // [0, 2048)
    const float* csn = ws + CS_OFFC;
    unsigned Mv = (unsigned)m ^ ((unsigned)m >> 4); // x bits 7..17

    const float* rb = ws + (((size_t)b << 18)
                    | (size_t)((Mv >> 3) & 7u)
                    | ((size_t)((Mv >> 6) & 7u) << 3)
                    | ((size_t)(Mv & 7u) << 6)
                    | ((size_t)((Mv >> 9) & 3u) << 16));
    v2f A[64];
    unroll<128>([&](auto N) {
        constexpr int n = N.value;
        constexpr unsigned off = (unsigned)(((n & 15) << 9) | ((n >> 4) << 13));
        seta<n>(A, rb[off]);
    });
    apply_gates2<0, 36, 18, 128>(A, Mv << 7, csn);

    unsigned cc = ((unsigned)m & 15u) << 3;
    float* obb = out + (((size_t)b << NQ) | ((size_t)(blockIdx.x & 7) << 15));
    const unsigned w6 = (unsigned)(t & 63);
    const unsigned Sw = (w6 << 7) ^ ((w6 << 1) & 28u);
    const int myQ = t >> 6;
    #pragma unroll
    for (int Q = 0; Q < 4; ++Q) {
        if (myQ == Q) {
            unroll<32>([&](auto Qd) {
                constexpr int n0 = Qd.value << 2;
                unsigned nx = (unsigned)n0 ^ cc;
                unsigned D  = (nx ^ (nx >> 4)) & 127u;
                unsigned Bq = Sw ^ (D & ~3u);
                float4 v = make_float4(geta<n0>(A), geta<n0 ^ 1>(A),
                                       geta<n0 ^ 2>(A), geta<n0 ^ 3>(A));
                *(float4*)&lds[Bq] = perm4(v, (int)(D & 3u));
            });
        }
        __syncthreads();
        float* ohQ = obb + ((size_t)Q << 13);
        unroll<8>([&](auto I) {
            constexpr int i = I.value;
            unsigned p0 = ((unsigned)(i * 256) + (unsigned)t) << 2;
            unsigned z0 = p0 ^ ((p0 >> 6) & 28u);
            *(float4*)&ohQ[z0] = *(const float4*)&lds[p0];
        });
        __syncthreads();
    }
}

// ======================= fallback (proven R5 path, no ws) =======================
__global__ __launch_bounds__(256) void k_init_f(const float* __restrict__ inputs,
                                                const float* __restrict__ params,
                                                float* __restrict__ S) {
    __shared__ float2 vt[2][NQ];
    int g = blockIdx.x * 256 + threadIdx.x;
    int b = g >> 13;
    int t = threadIdx.x;
    if (t < NQ) {
        float x = 0.5f * inputs[b * NQ + t];
        float cx = cosf(x), sx = sinf(x);
        float th = 0.5f * params[t];
        float c = cosf(th), s = sinf(th);
        vt[0][t] = make_float2(c * cx,  s * sx);
        vt[1][t] = make_float2(s * cx, -c * sx);
    }
    __syncthreads();
    unsigned OW = (unsigned)(g & 0x1FFF);
    unsigned iu = OW ^ (OW >> 1);
    int pu = OW & 1;
    float2 p = make_float2(1.f, 0.f);
    #pragma unroll
    for (int q = 0; q <= 12; ++q) {
        int bit = (iu >> (12 - q)) & 1;
        p = cmulf(p, vt[bit][q]);
    }
    float2 a[32];
    a[0] = p;
    #pragma unroll
    for (int bp = 0; bp < 5; ++bp) {
        float2 v0 = vt[0][17 - bp], v1 = vt[1][17 - bp];
        if (bp == 4 && pu) { float2 tt = v0; v0 = v1; v1 = tt; }
        #pragma unroll
        for (int i = (1 << bp) - 1; i >= 0; --i) {
            float2 base = a[i];
            a[i + (1 << bp)] = cmulf(base, v1);
            a[i] = cmulf(base, v0);
        }
    }
    float* outp = S + ((size_t)b << NQ) + ((size_t)OW << 5);
    #pragma unroll
    for (int oj = 0; oj < 32; oj += 4) {
        int k0 = oj ^ (oj >> 1);
        *(float4*)(outp + oj) = make_float4(a[k0].x, a[k0 ^ 1].x, a[k0 ^ 3].x, a[k0 ^ 2].x);
    }
}

template<int P>
__global__ __launch_bounds__(256) void k_pass_f(const float* __restrict__ params,
                                                float* __restrict__ S, int layer) {
    int g = blockIdx.x * 256 + threadIdx.x;
    float cg[6], sg[6];
    #pragma unroll
    for (int i = 0; i < 6; ++i) {
        float th = 0.5f * params[layer * NQ + 6 * P + i];
        cg[i] = cosf(th); sg[i] = sinf(th);
    }
    size_t base; int hm;
    constexpr int STR = (P == 0) ? 4096 : (P == 1) ? 64 : 1;
    if constexpr (P == 0) {
        base = ((size_t)(g >> 12) << NQ) | (size_t)(g & 0xFFF);
        hm = 0;
    } else if constexpr (P == 1) {
        base = ((size_t)(g >> 12) << NQ) | ((size_t)((g >> 6) & 63) << 12) | (size_t)(g & 63);
        hm = (g >> 6) & 1;
    } else {
        base = (size_t)g << 6;
        hm = g & 1;
    }
    float a[64];
    if constexpr (P == 2) {
        #pragma unroll
        for (int j = 0; j < 64; j += 4) {
            float4 w = *(const float4*)(S + base + j);
            a[j] = w.x; a[j + 1] = w.y; a[j + 2] = w.z; a[j + 3] = w.w;
        }
    } else {
        #pragma unroll
        for (int j = 0; j < 64; ++j) a[j] = S[base + (size_t)j * STR];
    }
    #pragma unroll
    for (int i = 0; i < 6; ++i) {
        int mm = 32 >> i;
        #pragma unroll
        for (int r = 0; r < 64; ++r) if (!(r & mm)) {
            float x0 = a[r], x1 = a[r | mm];
            a[r]      = cg[i] * x0 - sg[i] * x1;
            a[r | mm] = sg[i] * x0 + cg[i] * x1;
        }
    }
    if (hm) {
        #pragma unroll
        for (int r = 0; r < 32; ++r) { float tt = a[r]; a[r] = a[r ^ 32]; a[r ^ 32] = tt; }
    }
    if constexpr (P == 2) {
        #pragma unroll
        for (int oj = 0; oj < 64; oj += 4) {
            int k0 = oj ^ (oj >> 1);
            *(float4*)(S + base + oj) = make_float4(a[k0], a[k0 ^ 1], a[k0 ^ 3], a[k0 ^ 2]);
        }
    } else {
        #pragma unroll
        for (int oj = 0; oj < 64; ++oj)
            S[base + (size_t)oj * STR] = a[oj ^ (oj >> 1)];
    }
}

extern "C" void kernel_launch(void* const* d_in, const int* in_sizes, int n_in,
                              void* d_out, int out_size, void* d_ws, size_t ws_size,
                              hipStream_t stream) {
    const float* inputs = (const float*)d_in[0];   // (64, 18) f32
    const float* params = (const float*)d_in[1];   // (4, 18, 1) f32
    float* out = (float*)d_out;                    // (64, 2^18) f32 = Re(state)
    float* ws  = (float*)d_ws;
    const size_t need = (size_t)4 * ((1ull << 24) + BATCH * NQ * 4 + 108);

    if (ws_size >= need) {
        k_prep<<<5, 256, 0, stream>>>(inputs, params, ws);
        k_passA<<<BATCH * 16, 256, 0, stream>>>(ws, ws);
        k_passB<<<512, 256, 0, stream>>>(ws, out);
    } else {
        k_init_f<<<2048, 256, 0, stream>>>(inputs, params, out);
        for (int layer = 1; layer < 4; ++layer) {
            k_pass_f<0><<<1024, 256, 0, stream>>>(params, out, layer);
            k_pass_f<1><<<1024, 256, 0, stream>>>(params, out, layer);
            k_pass_f<2><<<1024, 256, 0, stream>>>(params, out, layer);
        }
    }
}

// Round 13
// 76.555 us; speedup vs baseline: 1.4135x; 1.0004x over previous
//
#include <hip/hip_runtime.h>
#include <utility>

#define NQ 18
#define BATCH 64

// ws float-offsets for the fast path
#define VT_OFFC (1u << 24)                      // 64*2^18 state floats first
#define CS_OFFC (VT_OFFC + BATCH * NQ * 4)      // then vt table, then cos/sin table

typedef float v2f __attribute__((ext_vector_type(2)));

__device__ __forceinline__ float2 cmulf(float2 a, float2 b) {
    return make_float2(a.x * b.x - a.y * b.y, a.x * b.y + a.y * b.x);
}

template<class F, int... Is>
__device__ __forceinline__ void unroll_impl(F f, std::integer_sequence<int, Is...>) {
    (f(std::integral_constant<int, Is>{}), ...);
}
template<int N, class F>
__device__ __forceinline__ void unroll(F f) {
    unroll_impl(f, std::make_integer_sequence<int, N>{});
}

// ---------------------------------------------------------------------------
// Gate algebra (storage order fixed = logical order at layer 1):
//  ladder = linear map T: s -> s ^ (s>>1)  (final[s] = pre[T s])
//  layer-k RY(qubit q), p = 17-q, conjugated to stored coords:
//    mask m = T^(k-1) e_p ; orientation O = row p of T^-(k-1)
//  Output perm: out[s] = A[T^4 s], T^4 s = s ^ (s>>4).
//
// Inter-pass ws layout: float offset = (x10..15) | (x7..9)<<6 | (x0..3)<<9
//                     | (x4..6)<<13 | (x16..17)<<16 | b<<18
// LDS tile swizzle slot(y) = y ^ ((y>>6)&31) is GF(2)-LINEAR -> per-phase
// addresses hoist to  slot(P_t) ^ slot(K_j)  (runtime base ^ compile-time K).
//
// Registers are PACKED as v2f: A[R] holds scalar amps (2R, 2R+1); vertical
// gates (mask bit0 clear) use v_pk_fma_f32-shaped vector ops.
//
// Sign classes: out-of-window orientation popc depends only on (k, p mod
// {1,2,4}) since O ⊆ bits ≥ p and window bits of xfix are zero -> hoist one
// popc per present class per phase instead of one per gate.
// ---------------------------------------------------------------------------
struct Gate { int k, p; };
constexpr Gate GT[54] = {
    // pass A phase 0, window x 12..17
    {2,13},{2,14},{2,15},{2,16},{2,17}, {3,14},{3,15},{3,16},{3,17}, {4,15},{4,16},{4,17},
    // phase 1, window x 10..15
    {2,11},{2,12}, {3,12},{3,13}, {4,13},{4,14},
    // phase 2, window x 7..12
    {2,8},{2,9},{2,10}, {3,9},{3,10},{3,11}, {4,10},{4,11},{4,12},
    // phase 3, window x 4..9
    {2,5},{2,6},{2,7}, {3,6},{3,7},{3,8}, {4,7},{4,8},{4,9},
    // pass B, window x 0..6
    {2,0},{2,1},{2,2},{2,3},{2,4},
    {3,0},{3,1},{3,2},{3,3},{3,4},{3,5},
    {4,0},{4,1},{4,2},{4,3},{4,4},{4,5},{4,6},
};
constexpr unsigned gmask(Gate g) {
    return g.k == 2 ? (g.p >= 1 ? 3u << (g.p - 1) : 1u)
         : g.k == 3 ? (g.p >= 2 ? 5u << (g.p - 2) : 1u << g.p)
         : (g.p >= 3 ? 15u << (g.p - 3) : (1u << (g.p + 1)) - 1u);
}
constexpr unsigned gorient(Gate g) {
    return g.k == 2 ? (0x3FFFFu & ~((1u << g.p) - 1u))
         : g.k == 3 ? ((0x15555u << g.p) & 0x3FFFFu)
         : ((0x33333u << g.p) & 0x3FFFFu);
}
constexpr int gcsi(Gate g) { return (g.k - 2) * NQ + (17 - g.p); }

// is sign-class (k, r) present among GT[OFF..OFF+NG)?
constexpr bool clsPresent(int OFF, int NG, int k, int r) {
    for (int i = 0; i < NG; ++i) {
        Gate g = GT[OFF + i];
        if (g.k == k) {
            int rr = (k == 2) ? 0 : (k == 3) ? (g.p & 1) : (g.p & 3);
            if (rr == r) return true;
        }
    }
    return false;
}

// Packed apply: NG gates on NR scalar regs held as v2f A[NR/2], window at x-bit WL.
template<int WL, int OFF, int NG, int NR>
__device__ __forceinline__ void apply_gates2(v2f* A, unsigned xfix, const float* csn) {
    constexpr int NR2 = NR / 2;
    constexpr unsigned HIM = 0x3FFFFu & ~((((unsigned)NR) << WL) - 1u);  // bits >= WL+w

    // hoisted per-class orientation parities (only classes actually present)
    int par2 = 0, par3[2] = {0, 0}, par4[4] = {0, 0, 0, 0};
    if constexpr (clsPresent(OFF, NG, 2, 0)) par2    = __popc(xfix & HIM) & 1;
    if constexpr (clsPresent(OFF, NG, 3, 0)) par3[0] = __popc(xfix & (HIM & 0x15555u)) & 1;
    if constexpr (clsPresent(OFF, NG, 3, 1)) par3[1] = __popc(xfix & (HIM & 0x2AAAAu)) & 1;
    if constexpr (clsPresent(OFF, NG, 4, 0)) par4[0] = __popc(xfix & (HIM & 0x33333u)) & 1;
    if constexpr (clsPresent(OFF, NG, 4, 1)) par4[1] = __popc(xfix & (HIM & 0x66666u)) & 1;
    if constexpr (clsPresent(OFF, NG, 4, 2)) par4[2] = __popc(xfix & (HIM & 0xCCCCCu)) & 1;
    if constexpr (clsPresent(OFF, NG, 4, 3)) par4[3] = __popc(xfix & (HIM & 0x99999u)) & 1;

    unroll<NG>([&](auto I) {
        constexpr Gate g = GT[OFF + I.value];
        constexpr unsigned m   = gmask(g);
        constexpr unsigned O   = gorient(g);
        constexpr unsigned mr  = (m >> WL) & (unsigned)(NR - 1);
        constexpr unsigned hb  = 1u << (g.p - WL);
        constexpr unsigned Or  = (O >> WL) & (unsigned)(NR - 1);
        constexpr unsigned Orf = Or >> 1;
        constexpr bool     Or0 = (Or & 1u) != 0;
        constexpr int clsR = (g.k == 2) ? 0 : (g.k == 3) ? (g.p & 1) : (g.p & 3);
        float c = csn[2 * gcsi(g)], s = csn[2 * gcsi(g) + 1];
        int par = (g.k == 2) ? par2 : (g.k == 3) ? par3[clsR] : par4[clsR];
        float psv = par ? -s : s;
        float msv = -psv;
        v2f cv; cv.x = c; cv.y = c;
        if constexpr ((mr & 1u) == 0u) {
            // vertical: partner preserves component; fully packed
            constexpr unsigned hbf = hb >> 1, mrf = mr >> 1;
            unroll<NR2>([&](auto RR) {
                constexpr int R = RR.value;
                if constexpr ((R & (int)hbf) == 0) {
                    constexpr int R2 = R ^ (int)mrf;
                    constexpr bool fl0 = (__builtin_popcount((unsigned)R & Orf) & 1) != 0;
                    constexpr bool fl1 = fl0 != Or0;
                    v2f sev; sev.x = fl0 ? msv : psv; sev.y = fl1 ? msv : psv;
                    v2f x0 = A[R], x1 = A[R2];
                    A[R]  = cv * x0 - sev * x1;
                    A[R2] = sev * x0 + cv * x1;
                }
            });
        } else if constexpr (mr == 1u) {
            // pure horizontal: pair inside the v2f; se from low elem (bit0=0)
            unroll<NR2>([&](auto RR) {
                constexpr int R = RR.value;
                constexpr bool fl0 = (__builtin_popcount((unsigned)R & Orf) & 1) != 0;
                float se0 = fl0 ? msv : psv;
                v2f v = A[R], nv;
                nv.x = c * v.x - se0 * v.y;
                nv.y = se0 * v.x + c * v.y;
                A[R] = nv;
            });
        } else {
            // crossed: partner of (R,c) is (R^mrf, c^1); pair sign = se(low r)
            constexpr unsigned hbf = hb >> 1, mrf = mr >> 1;
            unroll<NR2>([&](auto RR) {
                constexpr int R = RR.value;
                if constexpr ((R & (int)hbf) == 0) {
                    constexpr int R2 = R ^ (int)mrf;
                    constexpr bool fl0 = (__builtin_popcount((unsigned)R & Orf) & 1) != 0;
                    constexpr bool fl1 = fl0 != Or0;
                    v2f sev; sev.x = fl0 ? msv : psv; sev.y = fl1 ? msv : psv;
                    v2f x0 = A[R], x1 = A[R2];
                    v2f x1s = __builtin_shufflevector(x1, x1, 1, 0);
                    v2f t   = sev * x0;
                    v2f ts  = __builtin_shufflevector(t, t, 1, 0);
                    A[R]  = cv * x0 - sev * x1s;
                    A[R2] = ts + cv * x1;
                }
            });
        }
    });
}

// scalar access helpers: a[j] == (j&1) ? A[j>>1].y : A[j>>1].x  (j compile-time)
template<int J>
__device__ __forceinline__ float geta(const v2f* A) {
    if constexpr (J & 1) return A[J >> 1].y; else return A[J >> 1].x;
}
template<int J>
__device__ __forceinline__ void seta(v2f* A, float v) {
    if constexpr (J & 1) A[J >> 1].y = v; else A[J >> 1].x = v;
}

// component unpermute by XOR k (k in 0..3): t_c <- r_{c^k}
__device__ __forceinline__ float4 perm4(float4 r, int k) {
    float t0 = r.x, t1 = r.y, t2 = r.z, t3 = r.w;
    if (k & 1) { float x; x=t0;t0=t1;t1=x; x=t2;t2=t3;t3=x; }
    if (k & 2) { float x; x=t0;t0=t2;t2=x; x=t1;t1=t3;t3=x; }
    return make_float4(t0, t1, t2, t3);
}

// prep: vt[b][q] = RY(p0q/2)*RX(x/2)|0> (4 floats), plus cos/sin for layers 1..3
__global__ void k_prep(const float* __restrict__ inputs, const float* __restrict__ params,
                       float* __restrict__ ws) {
    int t = blockIdx.x * blockDim.x + threadIdx.x;
    if (t < BATCH * NQ) {
        int q = t % NQ;
        float x = 0.5f * inputs[t];
        float cx = cosf(x), sx = sinf(x);
        float th = 0.5f * params[q];
        float c = cosf(th), s = sinf(th);
        float* v = ws + VT_OFFC + t * 4;
        v[0] = c * cx;  v[1] = s * sx;     // v0 = c*cx + i*s*sx
        v[2] = s * cx;  v[3] = -c * sx;    // v1 = s*cx - i*c*sx
    } else if (t < BATCH * NQ + 54) {
        int i = t - BATCH * NQ;            // (k-2)*18 + q  -> params[(k-1)*18+q]
        float th = 0.5f * params[NQ + i];
        ws[CS_OFFC + 2 * i]     = cosf(th);
        ws[CS_OFFC + 2 * i + 1] = sinf(th);
    }
}

// pass A: init product (layer 0 folded) + 36 gates on x bits 4..17.
// WG = (b, c4 = x bits 0..3); tile = 2^14 f32 in LDS (4 gate phases).
// All LDS addresses hoisted: slot(P|K) = slot(P) ^ slot(K) (GF2-linear).
__global__ __launch_bounds__(256) void k_passA(const float* __restrict__ ws_tab,
                                               float* __restrict__ ws) {
    __shared__ __align__(16) float lds[16384];   // exactly 64 KiB
    const int b  = blockIdx.x >> 4;
    const int c4 = blockIdx.x & 15;
    const int t  = threadIdx.x;
    const float* vt  = ws_tab + VT_OFFC + b * NQ * 4;
    const float* csn = ws_tab + CS_OFFC;

    // init: complex product (depth-4 tree for ILP), reg bit bp <-> x bit 12+bp
    unsigned xf0 = (unsigned)c4 | ((unsigned)t << 4);   // x bits 0..11
    float2 f[12];
    #pragma unroll
    for (int i = 0; i < 12; ++i) {
        int bit = (xf0 >> i) & 1;
        const float* vq = vt + (17 - i) * 4 + bit * 2;
        f[i] = make_float2(vq[0], vq[1]);
    }
    f[0] = cmulf(f[0], f[1]);  f[2] = cmulf(f[2], f[3]);
    f[4] = cmulf(f[4], f[5]);  f[6] = cmulf(f[6], f[7]);
    f[8] = cmulf(f[8], f[9]);  f[10] = cmulf(f[10], f[11]);
    f[0] = cmulf(f[0], f[2]);  f[4] = cmulf(f[4], f[6]);  f[8] = cmulf(f[8], f[10]);
    f[0] = cmulf(f[0], f[4]);
    float2 pf = cmulf(f[0], f[8]);

    float2 ca[32];
    ca[0] = pf;
    #pragma unroll
    for (int bp = 0; bp < 5; ++bp) {
        const float* vq = vt + (5 - bp) * 4;
        float2 v0 = make_float2(vq[0], vq[1]), v1 = make_float2(vq[2], vq[3]);
        #pragma unroll
        for (int i = (1 << bp) - 1; i >= 0; --i) {
            float2 base = ca[i];
            ca[i + (1 << bp)] = cmulf(base, v1);
            ca[i] = cmulf(base, v0);
        }
    }
    v2f A[32];                             // scalar reg j: A[j>>1] comp j&1
    {
        const float* vq = vt;              // pack bit 5 <-> x bit 17 <-> qubit 0
        float2 v0 = make_float2(vq[0], vq[1]), v1 = make_float2(vq[2], vq[3]);
        unroll<16>([&](auto RR) {
            constexpr int R = RR.value;
            A[R].x      = ca[2*R].x   * v0.x - ca[2*R].y   * v0.y;
            A[R].y      = ca[2*R+1].x * v0.x - ca[2*R+1].y * v0.y;
            A[16+R].x   = ca[2*R].x   * v1.x - ca[2*R].y   * v1.y;
            A[16+R].y   = ca[2*R+1].x * v1.x - ca[2*R+1].y * v1.y;
        });
    }
    apply_gates2<12, 0, 12, 64>(A, xf0, csn);

    // ph0 write: y = (j<<8)|t, j = q*8+r.  slot = [St ^ r*260] + q*2048 (additive!)
    unsigned St = (unsigned)t ^ ((unsigned)t >> 6);
    unroll<8>([&](auto Rr) {
        constexpr int r = Rr.value;
        unsigned br = St ^ (unsigned)((r << 8) | (r << 2));
        unroll<8>([&](auto Qq) {
            constexpr int q = Qq.value;
            lds[br + (q << 11)] = geta<q * 8 + r>(A);
        });
    });
    __syncthreads();

    // ph1: y = base1 | (j<<6); slot(base1) = base1; K = (j<<6)|(j&31)
    unsigned Sb1 = (unsigned)(t & 63) | ((unsigned)(t >> 6) << 12);
    unroll<64>([&](auto J) {
        constexpr unsigned K = (unsigned)((J.value << 6) | (J.value & 31));
        seta<J.value>(A, lds[Sb1 ^ K]);
    });
    unsigned xf1 = (unsigned)c4 | ((unsigned)(t & 63) << 4) | ((unsigned)(t >> 6) << 16);
    apply_gates2<10, 12, 6, 64>(A, xf1, csn);
    unroll<64>([&](auto J) {
        constexpr unsigned K = (unsigned)((J.value << 6) | (J.value & 31));
        lds[Sb1 ^ K] = geta<J.value>(A);
    });
    __syncthreads();

    // ph2: y = base2 | (j<<3); slot(base2) = base2 ^ ((t>>3)&3)<<3; K = (j<<3)|(j>>3)
    unsigned Sb2 = ((unsigned)(t & 7) | ((unsigned)(t >> 3) << 9))
                 ^ ((((unsigned)t >> 3) & 3u) << 3);
    unroll<64>([&](auto J) {
        constexpr unsigned K = (unsigned)((J.value << 3) | (J.value >> 3));
        seta<J.value>(A, lds[Sb2 ^ K]);
    });
    unsigned xf2 = (unsigned)c4 | ((unsigned)(t & 7) << 4) | ((unsigned)(t >> 3) << 13);
    apply_gates2<7, 18, 9, 64>(A, xf2, csn);
    unroll<64>([&](auto J) {
        constexpr unsigned K = (unsigned)((J.value << 3) | (J.value >> 3));
        lds[Sb2 ^ K] = geta<J.value>(A);
    });
    __syncthreads();

    // ph3: y = j | (t<<6); slot(t<<6) = (t<<6)^(t&31); addr = Sb3 ^ j
    unsigned Sb3 = ((unsigned)t << 6) ^ ((unsigned)t & 31u);
    unroll<64>([&](auto J) {
        seta<J.value>(A, lds[Sb3 ^ (unsigned)J.value]);
    });
    unsigned xf3 = (unsigned)c4 | ((unsigned)t << 10);
    apply_gates2<4, 27, 9, 64>(A, xf3, csn);

    // direct stores: offset = (t&63) | (j>>3)<<6 | c4<<9 | (j&7)<<13 | (t>>6)<<16 | b<<18
    float* wp = ws + (((size_t)b << 18) | ((size_t)(t >> 6) << 16)
                      | ((size_t)c4 << 9) | (size_t)(t & 63));
    unroll<64>([&](auto J) {
        constexpr int j = J.value;
        constexpr unsigned off = (unsigned)(((j >> 3) << 6) | ((j & 7) << 13));
        wp[off] = geta<j>(A);
    });
}

// pass B: output-major. Thread m owns out floats s = m<<7 | d (contiguous 512B).
// Reads A[x], x0..6 free, x7..17 = M = m^(m>>4). 18 gates on x bits 0..6.
// Store via 32 KiB LDS quarter-staging (4 rounds, writer = one wave/round).
// NOTE: plain launch_bounds(256) — capping VGPRs spilled a[128] (R10).
__global__ __launch_bounds__(256) void k_passB(const float* __restrict__ ws,
                                               float* __restrict__ out) {
    __shared__ __align__(16) float lds[8192];    // 32 KiB
    const int t = threadIdx.x;
    const int b = blockIdx.x >> 3;               // 8 blocks per sample
    const int m = ((blockIdx.x & 7) << 8) | t;   // [0, 2048)
    const float* csn = ws + CS_OFFC;
    unsigned Mv = (unsigned)m ^ ((unsigned)m >> 4); // x bits 7..17

    const float* rb = ws + (((size_t)b << 18)
                    | (size_t)((Mv >> 3) & 7u)
                    | ((size_t)((Mv >> 6) & 7u) << 3)
                    | ((size_t)(Mv & 7u) << 6)
                    | ((size_t)((Mv >> 9) & 3u) << 16));
    v2f A[64];
    unroll<128>([&](auto N) {
        constexpr int n = N.value;
        constexpr unsigned off = (unsigned)(((n & 15) << 9) | ((n >> 4) << 13));
        seta<n>(A, rb[off]);
    });
    apply_gates2<0, 36, 18, 128>(A, Mv << 7, csn);

    unsigned cc = ((unsigned)m & 15u) << 3;
    float* obb = out + (((size_t)b << NQ) | ((size_t)(blockIdx.x & 7) << 15));
    const unsigned w6 = (unsigned)(t & 63);
    const unsigned Sw = (w6 << 7) ^ ((w6 << 1) & 28u);
    const int myQ = t >> 6;
    #pragma unroll
    for (int Q = 0; Q < 4; ++Q) {
        if (myQ == Q) {
            unroll<32>([&](auto Qd) {
                constexpr int n0 = Qd.value << 2;
                unsigned nx = (unsigned)n0 ^ cc;
                unsigned D  = (nx ^ (nx >> 4)) & 127u;
                unsigned Bq = Sw ^ (D & ~3u);
                float4 v = make_float4(geta<n0>(A), geta<n0 ^ 1>(A),
                                       geta<n0 ^ 2>(A), geta<n0 ^ 3>(A));
                *(float4*)&lds[Bq] = perm4(v, (int)(D & 3u));
            });
        }
        __syncthreads();
        float* ohQ = obb + ((size_t)Q << 13);
        unroll<8>([&](auto I) {
            constexpr int i = I.value;
            unsigned p0 = ((unsigned)(i * 256) + (unsigned)t) << 2;
            unsigned z0 = p0 ^ ((p0 >> 6) & 28u);
            *(float4*)&ohQ[z0] = *(const float4*)&lds[p0];
        });
        __syncthreads();
    }
}

// ======================= fallback (proven R5 path, no ws) =======================
__global__ __launch_bounds__(256) void k_init_f(const float* __restrict__ inputs,
                                                const float* __restrict__ params,
                                                float* __restrict__ S) {
    __shared__ float2 vt[2][NQ];
    int g = blockIdx.x * 256 + threadIdx.x;
    int b = g >> 13;
    int t = threadIdx.x;
    if (t < NQ) {
        float x = 0.5f * inputs[b * NQ + t];
        float cx = cosf(x), sx = sinf(x);
        float th = 0.5f * params[t];
        float c = cosf(th), s = sinf(th);
        vt[0][t] = make_float2(c * cx,  s * sx);
        vt[1][t] = make_float2(s * cx, -c * sx);
    }
    __syncthreads();
    unsigned OW = (unsigned)(g & 0x1FFF);
    unsigned iu = OW ^ (OW >> 1);
    int pu = OW & 1;
    float2 p = make_float2(1.f, 0.f);
    #pragma unroll
    for (int q = 0; q <= 12; ++q) {
        int bit = (iu >> (12 - q)) & 1;
        p = cmulf(p, vt[bit][q]);
    }
    float2 a[32];
    a[0] = p;
    #pragma unroll
    for (int bp = 0; bp < 5; ++bp) {
        float2 v0 = vt[0][17 - bp], v1 = vt[1][17 - bp];
        if (bp == 4 && pu) { float2 tt = v0; v0 = v1; v1 = tt; }
        #pragma unroll
        for (int i = (1 << bp) - 1; i >= 0; --i) {
            float2 base = a[i];
            a[i + (1 << bp)] = cmulf(base, v1);
            a[i] = cmulf(base, v0);
        }
    }
    float* outp = S + ((size_t)b << NQ) + ((size_t)OW << 5);
    #pragma unroll
    for (int oj = 0; oj < 32; oj += 4) {
        int k0 = oj ^ (oj >> 1);
        *(float4*)(outp + oj) = make_float4(a[k0].x, a[k0 ^ 1].x, a[k0 ^ 3].x, a[k0 ^ 2].x);
    }
}

template<int P>
__global__ __launch_bounds__(256) void k_pass_f(const float* __restrict__ params,
                                                float* __restrict__ S, int layer) {
    int g = blockIdx.x * 256 + threadIdx.x;
    float cg[6], sg[6];
    #pragma unroll
    for (int i = 0; i < 6; ++i) {
        float th = 0.5f * params[layer * NQ + 6 * P + i];
        cg[i] = cosf(th); sg[i] = sinf(th);
    }
    size_t base; int hm;
    constexpr int STR = (P == 0) ? 4096 : (P == 1) ? 64 : 1;
    if constexpr (P == 0) {
        base = ((size_t)(g >> 12) << NQ) | (size_t)(g & 0xFFF);
        hm = 0;
    } else if constexpr (P == 1) {
        base = ((size_t)(g >> 12) << NQ) | ((size_t)((g >> 6) & 63) << 12) | (size_t)(g & 63);
        hm = (g >> 6) & 1;
    } else {
        base = (size_t)g << 6;
        hm = g & 1;
    }
    float a[64];
    if constexpr (P == 2) {
        #pragma unroll
        for (int j = 0; j < 64; j += 4) {
            float4 w = *(const float4*)(S + base + j);
            a[j] = w.x; a[j + 1] = w.y; a[j + 2] = w.z; a[j + 3] = w.w;
        }
    } else {
        #pragma unroll
        for (int j = 0; j < 64; ++j) a[j] = S[base + (size_t)j * STR];
    }
    #pragma unroll
    for (int i = 0; i < 6; ++i) {
        int mm = 32 >> i;
        #pragma unroll
        for (int r = 0; r < 64; ++r) if (!(r & mm)) {
            float x0 = a[r], x1 = a[r | mm];
            a[r]      = cg[i] * x0 - sg[i] * x1;
            a[r | mm] = sg[i] * x0 + cg[i] * x1;
        }
    }
    if (hm) {
        #pragma unroll
        for (int r = 0; r < 32; ++r) { float tt = a[r]; a[r] = a[r ^ 32]; a[r ^ 32] = tt; }
    }
    if constexpr (P == 2) {
        #pragma unroll
        for (int oj = 0; oj < 64; oj += 4) {
            int k0 = oj ^ (oj >> 1);
            *(float4*)(S + base + oj) = make_float4(a[k0], a[k0 ^ 1], a[k0 ^ 3], a[k0 ^ 2]);
        }
    } else {
        #pragma unroll
        for (int oj = 0; oj < 64; ++oj)
            S[base + (size_t)oj * STR] = a[oj ^ (oj >> 1)];
    }
}

extern "C" void kernel_launch(void* const* d_in, const int* in_sizes, int n_in,
                              void* d_out, int out_size, void* d_ws, size_t ws_size,
                              hipStream_t stream) {
    const float* inputs = (const float*)d_in[0];   // (64, 18) f32
    const float* params = (const float*)d_in[1];   // (4, 18, 1) f32
    float* out = (float*)d_out;                    // (64, 2^18) f32 = Re(state)
    float* ws  = (float*)d_ws;
    const size_t need = (size_t)4 * ((1ull << 24) + BATCH * NQ * 4 + 108);

    if (ws_size >= need) {
        k_prep<<<5, 256, 0, stream>>>(inputs, params, ws);
        k_passA<<<BATCH * 16, 256, 0, stream>>>(ws, ws);
        k_passB<<<512, 256, 0, stream>>>(ws, out);
    } else {
        k_init_f<<<2048, 256, 0, stream>>>(inputs, params, out);
        for (int layer = 1; layer < 4; ++layer) {
            k_pass_f<0><<<1024, 256, 0, stream>>>(params, out, layer);
            k_pass_f<1><<<1024, 256, 0, stream>>>(params, out, layer);
            k_pass_f<2><<<1024, 256, 0, stream>>>(params, out, layer);
        }
    }
}